// Round 1
// baseline (1755.818 us; speedup 1.0000x reference)
//
#include <hip/hip_runtime.h>

#define DIM 4096
#define NH 32
#define NKV 8
#define HD 128
#define WINDOW 1024
#define SEQ 2048

typedef unsigned int uint32;
typedef __attribute__((ext_vector_type(8))) short short8_t;
typedef __attribute__((ext_vector_type(8))) __bf16 bf16x8_t;
typedef __attribute__((ext_vector_type(4))) float floatx4_t;

__device__ __forceinline__ uint32 f2bf_bits(float f) {
  uint32 u = __builtin_bit_cast(uint32, f);
  return (u + 0x7fffu + ((u >> 16) & 1u)) >> 16;
}
__device__ __forceinline__ float bf2f(unsigned short b) {
  return __builtin_bit_cast(float, ((uint32)b) << 16);
}

template <class X, class Y> struct same_t { static constexpr bool v = false; };
template <class X> struct same_t<X, X> { static constexpr bool v = true; };

// C[M,N] = A[M,K] * B[N,K]^T ; internal bf16 MFMA, fp32 accumulate.
// TA in {float, unsigned short(bf16)}, TC in {float, unsigned short(bf16)}.
// 128x128 tile, BK=64, 4 waves each owning a 64x64 quadrant (4x4 MFMA tiles).
template <typename TA, typename TC>
__global__ __launch_bounds__(256) void gemm_bt(const TA* __restrict__ A,
                                               const float* __restrict__ B,
                                               TC* __restrict__ C,
                                               int M, int N, int K) {
  // LDS row stride 72 bf16 = 144 B (== 4 banks mod 32) -> 2-way conflicts (free)
  __shared__ unsigned short As[128 * 72];
  __shared__ unsigned short Bs[128 * 72];
  const int tid = threadIdx.x;
  const int lane = tid & 63, w = tid >> 6;
  const int quad = lane >> 4, l16 = lane & 15;
  const int wm = w >> 1, wn = w & 1;
  const size_t m0 = (size_t)blockIdx.y * 128, n0 = (size_t)blockIdx.x * 128;

  floatx4_t acc[4][4] = {};

  const int nk = K >> 6;
  for (int kt = 0; kt < nk; kt++) {
    const int kbase = kt << 6;
    // ---- stage A tile (128 rows x 64 k) ----
    if constexpr (same_t<TA, float>::v) {
#pragma unroll
      for (int i = 0; i < 8; i++) {
        int f = tid + (i << 8);
        int row = f >> 4, col = (f & 15) << 2;
        const float4 val = *(const float4*)(A + (m0 + row) * (size_t)K + kbase + col);
        uint32 lo = f2bf_bits(val.x) | (f2bf_bits(val.y) << 16);
        uint32 hi = f2bf_bits(val.z) | (f2bf_bits(val.w) << 16);
        *(uint2*)(&As[row * 72 + col]) = make_uint2(lo, hi);
      }
    } else {
#pragma unroll
      for (int i = 0; i < 4; i++) {
        int f = tid + (i << 8);
        int row = f >> 3, col = (f & 7) << 3;
        short8_t v = *(const short8_t*)(A + (m0 + row) * (size_t)K + kbase + col);
        *(short8_t*)(&As[row * 72 + col]) = v;
      }
    }
    // ---- stage B tile (128 n-rows x 64 k), always fp32 source ----
#pragma unroll
    for (int i = 0; i < 8; i++) {
      int f = tid + (i << 8);
      int row = f >> 4, col = (f & 15) << 2;
      const float4 val = *(const float4*)(B + (n0 + row) * (size_t)K + kbase + col);
      uint32 lo = f2bf_bits(val.x) | (f2bf_bits(val.y) << 16);
      uint32 hi = f2bf_bits(val.z) | (f2bf_bits(val.w) << 16);
      *(uint2*)(&Bs[row * 72 + col]) = make_uint2(lo, hi);
    }
    __syncthreads();
#pragma unroll
    for (int ks = 0; ks < 2; ks++) {
      bf16x8_t af[4], bfg[4];
#pragma unroll
      for (int i = 0; i < 4; i++)
        af[i] = __builtin_bit_cast(bf16x8_t,
            *(const short8_t*)(&As[(wm * 64 + i * 16 + l16) * 72 + ks * 32 + quad * 8]));
#pragma unroll
      for (int j = 0; j < 4; j++)
        bfg[j] = __builtin_bit_cast(bf16x8_t,
            *(const short8_t*)(&Bs[(wn * 64 + j * 16 + l16) * 72 + ks * 32 + quad * 8]));
#pragma unroll
      for (int i = 0; i < 4; i++)
#pragma unroll
        for (int j = 0; j < 4; j++)
          acc[i][j] = __builtin_amdgcn_mfma_f32_16x16x32_bf16(af[i], bfg[j], acc[i][j], 0, 0, 0);
    }
    __syncthreads();
  }
  // ---- epilogue: C/D layout col=lane&15, row=quad*4+r ----
#pragma unroll
  for (int i = 0; i < 4; i++) {
#pragma unroll
    for (int j = 0; j < 4; j++) {
#pragma unroll
      for (int r = 0; r < 4; r++) {
        size_t row = m0 + wm * 64 + i * 16 + quad * 4 + r;
        size_t col = n0 + wn * 64 + j * 16 + l16;
        float v = acc[i][j][r];
        if constexpr (same_t<TC, float>::v)
          C[row * (size_t)N + col] = v;
        else
          C[row * (size_t)N + col] = (unsigned short)f2bf_bits(v);
      }
    }
  }
}

// In-place RoPE on bf16 tensor [S, H, 128]; one thread per (even,odd) pair.
__global__ __launch_bounds__(256) void rope_kernel(unsigned short* __restrict__ t,
                                                   const float* __restrict__ cosp,
                                                   const float* __restrict__ sinp,
                                                   int H) {
  const int idx = blockIdx.x * 256 + threadIdx.x;
  const int j = idx & 63;
  const int rem = idx >> 6;
  const int hh = rem % H;
  const int s = rem / H;
  const size_t base = ((size_t)s * H + hh) * 128 + (j << 1);
  const float t0 = bf2f(t[base]), t1 = bf2f(t[base + 1]);
  const float c = cosp[s * 64 + j], sn = sinp[s * 64 + j];
  t[base] = (unsigned short)f2bf_bits(t0 * c - t1 * sn);
  t[base + 1] = (unsigned short)f2bf_bits(t0 * sn + t1 * c);
}

// v [S, NKV*128] bf16 -> vT [NKV*128, S] bf16 (keys contiguous for PV B-frags)
__global__ __launch_bounds__(256) void vtrans_kernel(const unsigned short* __restrict__ v,
                                                     unsigned short* __restrict__ vT) {
  const int idx = blockIdx.x * 256 + threadIdx.x;
  const int s = idx >> 10;
  const int r = idx & 1023;
  vT[(size_t)r * SEQ + s] = v[idx];
}

// Flash attention: block = (qtile of 16, head). 128-key chunks, online softmax.
__global__ __launch_bounds__(256) void attn_kernel(const unsigned short* __restrict__ qb,
                                                   const unsigned short* __restrict__ kb,
                                                   const unsigned short* __restrict__ vT,
                                                   unsigned short* __restrict__ attn_out) {
  const int qt = blockIdx.x, h = blockIdx.y;
  const int q0 = qt * 16;
  const int kvh = h >> 2;
  const int tid = threadIdx.x;
  const int lane = tid & 63, w = tid >> 6;
  const int quad = lane >> 4, l16 = lane & 15;
  const float scale = 0.08838834764831845f;  // 128^-0.5

  __shared__ unsigned short Qs[16 * 136];  // stride 136 -> 2-way bank conflicts
  __shared__ float Sc[16 * 132];           // stride 132 -> 2-way bank conflicts
  __shared__ float m_run[16], l_run[16], alpha_sh[16];

  {
    int row = tid >> 4, col = (tid & 15) << 3;
    *(short8_t*)(&Qs[row * 136 + col]) =
        *(const short8_t*)(qb + (size_t)(q0 + row) * 4096 + h * 128 + col);
  }
  if (tid < 16) { m_run[tid] = -3e38f; l_run[tid] = 0.0f; }
  __syncthreads();

  bf16x8_t aq[4];
#pragma unroll
  for (int ks = 0; ks < 4; ks++)
    aq[ks] = __builtin_bit_cast(bf16x8_t,
        *(const short8_t*)(&Qs[l16 * 136 + ks * 32 + quad * 8]));

  floatx4_t o0 = {}, o1 = {};

  int kbeg = q0 - (WINDOW - 1); if (kbeg < 0) kbeg = 0;
  const int c0 = kbeg & ~127;
  const int nch = (q0 + 16 - c0 + 127) >> 7;

  for (int ci = 0; ci < nch; ci++) {
    const int kb0 = c0 + (ci << 7);
    // ---- scores: wave w owns key subtiles 2w, 2w+1 ----
#pragma unroll
    for (int sti = 0; sti < 2; sti++) {
      const int st = w * 2 + sti;
      const int key = kb0 + st * 16 + l16;
      const unsigned short* kp = kb + (size_t)key * 1024 + kvh * 128 + quad * 8;
      floatx4_t acc = {};
#pragma unroll
      for (int ks = 0; ks < 4; ks++) {
        bf16x8_t bfk = __builtin_bit_cast(bf16x8_t, *(const short8_t*)(kp + ks * 32));
        acc = __builtin_amdgcn_mfma_f32_16x16x32_bf16(aq[ks], bfk, acc, 0, 0, 0);
      }
#pragma unroll
      for (int r = 0; r < 4; r++) {
        const int il = quad * 4 + r;
        const int i = q0 + il;
        const bool ok = (key <= i) && (i - key < WINDOW);
        Sc[il * 132 + st * 16 + l16] = ok ? acc[r] * scale : -3e38f;
      }
    }
    __syncthreads();
    // ---- online softmax: 16 threads per row ----
    {
      const int row = tid >> 4, t = tid & 15;
      float* sr = &Sc[row * 132];
      float mx = -3e38f;
#pragma unroll
      for (int c = 0; c < 8; c++) mx = fmaxf(mx, sr[t + c * 16]);
#pragma unroll
      for (int m = 1; m < 16; m <<= 1) mx = fmaxf(mx, __shfl_xor(mx, m, 16));
      const float mold = m_run[row];
      const float mnew = fmaxf(mold, mx);
      float sum = 0.0f;
#pragma unroll
      for (int c = 0; c < 8; c++) {
        float sv = sr[t + c * 16];
        float p = (sv < -1e37f) ? 0.0f : __expf(sv - mnew);
        sr[t + c * 16] = p;
        sum += p;
      }
#pragma unroll
      for (int m = 1; m < 16; m <<= 1) sum += __shfl_xor(sum, m, 16);
      if (t == 0) {
        const float al = __expf(mold - mnew);  // mold==mnew==-3e38 -> 1.0, O==0: fine
        alpha_sh[row] = al;
        m_run[row] = mnew;
        l_run[row] = l_run[row] * al + sum;
      }
    }
    __syncthreads();
    // ---- PV: wave w owns dim tiles 2w, 2w+1 ----
#pragma unroll
    for (int nti = 0; nti < 2; nti++) {
      const int nt = w * 2 + nti;
      floatx4_t& o = nti ? o1 : o0;
#pragma unroll
      for (int r = 0; r < 4; r++) o[r] *= alpha_sh[quad * 4 + r];
      const unsigned short* vp = vT + (size_t)(kvh * 128 + nt * 16 + l16) * SEQ + kb0 + quad * 8;
#pragma unroll
      for (int ks = 0; ks < 4; ks++) {
        const float* pp = &Sc[l16 * 132 + ks * 32 + quad * 8];
        short8_t as;
#pragma unroll
        for (int jj = 0; jj < 8; jj++) as[jj] = (short)f2bf_bits(pp[jj]);
        bf16x8_t af = __builtin_bit_cast(bf16x8_t, as);
        bf16x8_t bfv = __builtin_bit_cast(bf16x8_t, *(const short8_t*)(vp + ks * 32));
        o = __builtin_amdgcn_mfma_f32_16x16x32_bf16(af, bfv, o, 0, 0, 0);
      }
    }
    __syncthreads();
  }
  // ---- epilogue ----
#pragma unroll
  for (int nti = 0; nti < 2; nti++) {
    const int nt = w * 2 + nti;
    const floatx4_t& o = nti ? o1 : o0;
#pragma unroll
    for (int r = 0; r < 4; r++) {
      const int row = quad * 4 + r;
      float v = o[r] / l_run[row];
      attn_out[(size_t)(q0 + row) * 4096 + h * 128 + nt * 16 + l16] =
          (unsigned short)f2bf_bits(v);
    }
  }
}

extern "C" void kernel_launch(void* const* d_in, const int* in_sizes, int n_in,
                              void* d_out, int out_size, void* d_ws, size_t ws_size,
                              hipStream_t stream) {
  (void)in_sizes; (void)n_in; (void)out_size; (void)ws_size;
  const float* x    = (const float*)d_in[0];
  const float* wq   = (const float*)d_in[1];
  const float* wk   = (const float*)d_in[2];
  const float* wv   = (const float*)d_in[3];
  const float* wo   = (const float*)d_in[4];
  const float* cosp = (const float*)d_in[5];
  const float* sinp = (const float*)d_in[6];
  float* out = (float*)d_out;

  char* ws = (char*)d_ws;
  unsigned short* qb    = (unsigned short*)(ws);                         // 16 MB
  unsigned short* kbuf  = (unsigned short*)(ws + 16777216);              // 4 MB
  unsigned short* vbuf  = (unsigned short*)(ws + 16777216 + 4194304);    // 4 MB
  unsigned short* vTb   = (unsigned short*)(ws + 16777216 + 2*4194304);  // 4 MB
  unsigned short* attnb = (unsigned short*)(ws + 16777216 + 3*4194304);  // 16 MB

  gemm_bt<float, unsigned short><<<dim3(32, 16), 256, 0, stream>>>(x, wq, qb, SEQ, 4096, DIM);
  gemm_bt<float, unsigned short><<<dim3(8, 16), 256, 0, stream>>>(x, wk, kbuf, SEQ, 1024, DIM);
  gemm_bt<float, unsigned short><<<dim3(8, 16), 256, 0, stream>>>(x, wv, vbuf, SEQ, 1024, DIM);
  rope_kernel<<<SEQ * NH * 64 / 256, 256, 0, stream>>>(qb, cosp, sinp, NH);
  rope_kernel<<<SEQ * NKV * 64 / 256, 256, 0, stream>>>(kbuf, cosp, sinp, NKV);
  vtrans_kernel<<<SEQ * NKV * HD / 256, 256, 0, stream>>>(vbuf, vTb);
  attn_kernel<<<dim3(SEQ / 16, NH), 256, 0, stream>>>(qb, kbuf, vTb, attnb);
  gemm_bt<unsigned short, float><<<dim3(32, 16), 256, 0, stream>>>(attnb, wo, out, SEQ, 4096, DIM);
}

// Round 2
// 689.913 us; speedup vs baseline: 2.5450x; 2.5450x over previous
//
#include <hip/hip_runtime.h>

#define DIM 4096
#define NH 32
#define NKV 8
#define HD 128
#define WINDOW 1024
#define SEQ 2048

typedef unsigned int uint32;
typedef __attribute__((ext_vector_type(8))) short short8_t;
typedef __attribute__((ext_vector_type(8))) __bf16 bf16x8_t;
typedef __attribute__((ext_vector_type(4))) float floatx4_t;

__device__ __forceinline__ uint32 f2bf_bits(float f) {
  uint32 u = __builtin_bit_cast(uint32, f);
  return (u + 0x7fffu + ((u >> 16) & 1u)) >> 16;
}
__device__ __forceinline__ float bf2f(unsigned short b) {
  return __builtin_bit_cast(float, ((uint32)b) << 16);
}

template <class X, class Y> struct same_t { static constexpr bool v = false; };
template <class X> struct same_t<X, X> { static constexpr bool v = true; };

__device__ __forceinline__ void load_lds16(const unsigned short* g, unsigned short* l) {
  __builtin_amdgcn_global_load_lds((__attribute__((address_space(1))) void*)g,
                                   (__attribute__((address_space(3))) void*)l, 16, 0, 0);
}

// ============================================================================
// bf16 GEMM, m97-style: C[M,N] = A[M,K] * B[N,K]^T, A/B bf16, global_load_lds
// width-16 staging into unpadded LDS with XOR col8 swizzle (applied on the
// global-read side). 128x128 tile, BK=64, 4 waves x (4x4) 16x16x32 MFMA.
// ============================================================================
template <typename TC>
__global__ __launch_bounds__(256) void gemm_bf16(const unsigned short* __restrict__ A,
                                                 const unsigned short* __restrict__ B,
                                                 TC* __restrict__ C,
                                                 int M, int N, int K) {
  __shared__ unsigned short As[128 * 64];  // row-major [row][k], no pad (lds-direct)
  __shared__ unsigned short Bs[128 * 64];
  const int tid = threadIdx.x;
  const int lane = tid & 63, w = tid >> 6;
  const int quad = lane >> 4, l16 = lane & 15;
  const int wm = w >> 1, wn = w & 1;
  const size_t m0 = (size_t)blockIdx.y * 128, n0 = (size_t)blockIdx.x * 128;

  // staging: thread covers rows srow + i*32, 16B chunk at swizzled col8
  const int srow = tid >> 3;                               // 0..31
  const int scol = ((tid & 7) ^ (srow & 7)) << 3;          // element col, XOR swizzle
  const unsigned short* Abase = A + (m0 + srow) * (size_t)K + scol;
  const unsigned short* Bbase = B + (n0 + srow) * (size_t)K + scol;
  unsigned short* ldsA = As + (tid >> 6) * 512;            // wave-uniform base
  unsigned short* ldsB = Bs + (tid >> 6) * 512;

  // fragment-read swizzle: row r -> col8' = col8 ^ (r & 7); r&7 == l16&7 here
  const int sa = l16 & 7;
  const int raA = wm * 64 + l16;
  const int raB = wn * 64 + l16;

  floatx4_t acc[4][4] = {};

  const int nk = K >> 6;
  for (int kt = 0; kt < nk; kt++) {
    const int kbase = kt << 6;
#pragma unroll
    for (int i = 0; i < 4; i++) {
      load_lds16(Abase + kbase + (size_t)(i * 32) * K, ldsA + i * 2048);
      load_lds16(Bbase + kbase + (size_t)(i * 32) * K, ldsB + i * 2048);
    }
    __syncthreads();
#pragma unroll
    for (int ks = 0; ks < 2; ks++) {
      bf16x8_t af[4], bfg[4];
#pragma unroll
      for (int i = 0; i < 4; i++) {
        const int colA = (((ks << 2) | quad) ^ sa) << 3;
        af[i] = __builtin_bit_cast(bf16x8_t,
            *(const short8_t*)(&As[(raA + i * 16) * 64 + colA]));
      }
#pragma unroll
      for (int j = 0; j < 4; j++) {
        const int colB = (((ks << 2) | quad) ^ sa) << 3;
        bfg[j] = __builtin_bit_cast(bf16x8_t,
            *(const short8_t*)(&Bs[(raB + j * 16) * 64 + colB]));
      }
#pragma unroll
      for (int i = 0; i < 4; i++)
#pragma unroll
        for (int j = 0; j < 4; j++)
          acc[i][j] = __builtin_amdgcn_mfma_f32_16x16x32_bf16(af[i], bfg[j], acc[i][j], 0, 0, 0);
    }
    __syncthreads();
  }
#pragma unroll
  for (int i = 0; i < 4; i++)
#pragma unroll
    for (int j = 0; j < 4; j++)
#pragma unroll
      for (int r = 0; r < 4; r++) {
        size_t row = m0 + wm * 64 + i * 16 + quad * 4 + r;
        size_t col = n0 + wn * 64 + j * 16 + l16;
        float v = acc[i][j][r];
        if constexpr (same_t<TC, float>::v)
          C[row * (size_t)N + col] = v;
        else
          C[row * (size_t)N + col] = (unsigned short)f2bf_bits(v);
      }
}

// ============================================================================
// Fallback fp32-staging GEMM (round-0, known-good) with ldc/col-offset.
// ============================================================================
template <typename TA, typename TC>
__global__ __launch_bounds__(256) void gemm_bt(const TA* __restrict__ A,
                                               const float* __restrict__ B,
                                               TC* __restrict__ C,
                                               int M, int N, int K, int ldc, int coff) {
  __shared__ unsigned short As[128 * 72];
  __shared__ unsigned short Bs[128 * 72];
  const int tid = threadIdx.x;
  const int lane = tid & 63, w = tid >> 6;
  const int quad = lane >> 4, l16 = lane & 15;
  const int wm = w >> 1, wn = w & 1;
  const size_t m0 = (size_t)blockIdx.y * 128, n0 = (size_t)blockIdx.x * 128;
  floatx4_t acc[4][4] = {};
  const int nk = K >> 6;
  for (int kt = 0; kt < nk; kt++) {
    const int kbase = kt << 6;
    if constexpr (same_t<TA, float>::v) {
#pragma unroll
      for (int i = 0; i < 8; i++) {
        int f = tid + (i << 8);
        int row = f >> 4, col = (f & 15) << 2;
        const float4 val = *(const float4*)(A + (m0 + row) * (size_t)K + kbase + col);
        uint32 lo = f2bf_bits(val.x) | (f2bf_bits(val.y) << 16);
        uint32 hi = f2bf_bits(val.z) | (f2bf_bits(val.w) << 16);
        *(uint2*)(&As[row * 72 + col]) = make_uint2(lo, hi);
      }
    } else {
#pragma unroll
      for (int i = 0; i < 4; i++) {
        int f = tid + (i << 8);
        int row = f >> 3, col = (f & 7) << 3;
        short8_t v = *(const short8_t*)(A + (m0 + row) * (size_t)K + kbase + col);
        *(short8_t*)(&As[row * 72 + col]) = v;
      }
    }
#pragma unroll
    for (int i = 0; i < 8; i++) {
      int f = tid + (i << 8);
      int row = f >> 4, col = (f & 15) << 2;
      const float4 val = *(const float4*)(B + (n0 + row) * (size_t)K + kbase + col);
      uint32 lo = f2bf_bits(val.x) | (f2bf_bits(val.y) << 16);
      uint32 hi = f2bf_bits(val.z) | (f2bf_bits(val.w) << 16);
      *(uint2*)(&Bs[row * 72 + col]) = make_uint2(lo, hi);
    }
    __syncthreads();
#pragma unroll
    for (int ks = 0; ks < 2; ks++) {
      bf16x8_t af[4], bfg[4];
#pragma unroll
      for (int i = 0; i < 4; i++)
        af[i] = __builtin_bit_cast(bf16x8_t,
            *(const short8_t*)(&As[(wm * 64 + i * 16 + l16) * 72 + ks * 32 + quad * 8]));
#pragma unroll
      for (int j = 0; j < 4; j++)
        bfg[j] = __builtin_bit_cast(bf16x8_t,
            *(const short8_t*)(&Bs[(wn * 64 + j * 16 + l16) * 72 + ks * 32 + quad * 8]));
#pragma unroll
      for (int i = 0; i < 4; i++)
#pragma unroll
        for (int j = 0; j < 4; j++)
          acc[i][j] = __builtin_amdgcn_mfma_f32_16x16x32_bf16(af[i], bfg[j], acc[i][j], 0, 0, 0);
    }
    __syncthreads();
  }
#pragma unroll
  for (int i = 0; i < 4; i++)
#pragma unroll
    for (int j = 0; j < 4; j++)
#pragma unroll
      for (int r = 0; r < 4; r++) {
        size_t row = m0 + wm * 64 + i * 16 + quad * 4 + r;
        size_t col = n0 + wn * 64 + j * 16 + l16;
        float v = acc[i][j][r];
        if constexpr (same_t<TC, float>::v)
          C[row * (size_t)ldc + coff + col] = v;
        else
          C[row * (size_t)ldc + coff + col] = (unsigned short)f2bf_bits(v);
      }
}

// fp32 -> bf16 convert, 8 elems/thread
__global__ __launch_bounds__(256) void cvt_kernel(const float* __restrict__ in,
                                                  unsigned short* __restrict__ out, int n8) {
  int idx = blockIdx.x * 256 + threadIdx.x;
  if (idx >= n8) return;
  const float4* p = (const float4*)in + (size_t)idx * 2;
  float4 a = p[0], b = p[1];
  uint32 w0 = f2bf_bits(a.x) | (f2bf_bits(a.y) << 16);
  uint32 w1 = f2bf_bits(a.z) | (f2bf_bits(a.w) << 16);
  uint32 w2 = f2bf_bits(b.x) | (f2bf_bits(b.y) << 16);
  uint32 w3 = f2bf_bits(b.z) | (f2bf_bits(b.w) << 16);
  ((uint4*)out)[idx] = make_uint4(w0, w1, w2, w3);
}

// In-place RoPE on bf16 tensor, rows s with leading dim ld, H heads of 128.
__global__ __launch_bounds__(256) void rope_kernel(unsigned short* __restrict__ t,
                                                   const float* __restrict__ cosp,
                                                   const float* __restrict__ sinp,
                                                   int H, int ld) {
  const int idx = blockIdx.x * 256 + threadIdx.x;
  const int j = idx & 63;
  const int rem = idx >> 6;
  const int hh = rem % H;
  const int s = rem / H;
  const size_t base = (size_t)s * ld + hh * 128 + (j << 1);
  const float t0 = bf2f(t[base]), t1 = bf2f(t[base + 1]);
  const float c = cosp[s * 64 + j], sn = sinp[s * 64 + j];
  t[base] = (unsigned short)f2bf_bits(t0 * c - t1 * sn);
  t[base + 1] = (unsigned short)f2bf_bits(t0 * sn + t1 * c);
}

// v [s][r] (ld 2048, caller passes pointer at col offset) -> vT [r][s], 64x64 LDS tiles
__global__ __launch_bounds__(256) void vtrans_kernel(const unsigned short* __restrict__ v,
                                                     unsigned short* __restrict__ vT) {
  __shared__ unsigned short t[64][72];
  const int s0 = blockIdx.y * 64, r0 = blockIdx.x * 64;
  const int tid = threadIdx.x;
#pragma unroll
  for (int it = 0; it < 2; it++) {
    int f = it * 256 + tid;
    int si = f >> 3, cj = (f & 7) << 3;
    *(short8_t*)(&t[si][cj]) = *(const short8_t*)(v + (size_t)(s0 + si) * 2048 + r0 + cj);
  }
  __syncthreads();
#pragma unroll
  for (int it = 0; it < 2; it++) {
    int f = it * 256 + tid;
    int ri = f >> 3, sj = (f & 7) << 3;
    short8_t o;
#pragma unroll
    for (int jj = 0; jj < 8; jj++) o[jj] = t[sj + jj][ri];
    *(short8_t*)(vT + (size_t)(r0 + ri) * SEQ + s0 + sj) = o;
  }
}

// Flash attention: block = (qtile of 16, head). 128-key chunks, online softmax.
// kb is the fused kv buffer (ld 2048, k in cols 0..1023).
__global__ __launch_bounds__(256) void attn_kernel(const unsigned short* __restrict__ qb,
                                                   const unsigned short* __restrict__ kb,
                                                   const unsigned short* __restrict__ vT,
                                                   unsigned short* __restrict__ attn_out) {
  const int qt = blockIdx.x, h = blockIdx.y;
  const int q0 = qt * 16;
  const int kvh = h >> 2;
  const int tid = threadIdx.x;
  const int lane = tid & 63, w = tid >> 6;
  const int quad = lane >> 4, l16 = lane & 15;
  const float scale = 0.08838834764831845f;  // 128^-0.5

  __shared__ unsigned short Qs[16 * 136];
  __shared__ float Sc[16 * 132];
  __shared__ unsigned short Ps[16 * 136];  // P in bf16 (A-operand layout rows)
  __shared__ float m_run[16], l_run[16], alpha_sh[16];

  {
    int row = tid >> 4, col = (tid & 15) << 3;
    *(short8_t*)(&Qs[row * 136 + col]) =
        *(const short8_t*)(qb + (size_t)(q0 + row) * 4096 + h * 128 + col);
  }
  if (tid < 16) { m_run[tid] = -3e38f; l_run[tid] = 0.0f; }
  __syncthreads();

  bf16x8_t aq[4];
#pragma unroll
  for (int ks = 0; ks < 4; ks++)
    aq[ks] = __builtin_bit_cast(bf16x8_t,
        *(const short8_t*)(&Qs[l16 * 136 + ks * 32 + quad * 8]));

  floatx4_t o0 = {}, o1 = {};

  int kbeg = q0 - (WINDOW - 1); if (kbeg < 0) kbeg = 0;
  const int c0 = kbeg & ~127;
  const int nch = (q0 + 16 - c0 + 127) >> 7;

  for (int ci = 0; ci < nch; ci++) {
    const int kb0 = c0 + (ci << 7);
#pragma unroll
    for (int sti = 0; sti < 2; sti++) {
      const int st = w * 2 + sti;
      const int key = kb0 + st * 16 + l16;
      const unsigned short* kp = kb + (size_t)key * 2048 + kvh * 128 + quad * 8;
      floatx4_t acc = {};
#pragma unroll
      for (int ks = 0; ks < 4; ks++) {
        bf16x8_t bfk = __builtin_bit_cast(bf16x8_t, *(const short8_t*)(kp + ks * 32));
        acc = __builtin_amdgcn_mfma_f32_16x16x32_bf16(aq[ks], bfk, acc, 0, 0, 0);
      }
#pragma unroll
      for (int r = 0; r < 4; r++) {
        const int il = quad * 4 + r;
        const int i = q0 + il;
        const bool ok = (key <= i) && (i - key < WINDOW);
        Sc[il * 132 + st * 16 + l16] = ok ? acc[r] * scale : -3e38f;
      }
    }
    __syncthreads();
    {
      const int row = tid >> 4, t = tid & 15;
      const float* sr = &Sc[row * 132];
      float mx = -3e38f;
#pragma unroll
      for (int c = 0; c < 8; c++) mx = fmaxf(mx, sr[t + c * 16]);
#pragma unroll
      for (int m = 1; m < 16; m <<= 1) mx = fmaxf(mx, __shfl_xor(mx, m, 16));
      const float mold = m_run[row];
      const float mnew = fmaxf(mold, mx);
      float sum = 0.0f;
#pragma unroll
      for (int c = 0; c < 8; c++) {
        float sv = sr[t + c * 16];
        float p = (sv < -1e37f) ? 0.0f : __expf(sv - mnew);
        Ps[row * 136 + t + c * 16] = (unsigned short)f2bf_bits(p);
        sum += p;
      }
#pragma unroll
      for (int m = 1; m < 16; m <<= 1) sum += __shfl_xor(sum, m, 16);
      if (t == 0) {
        const float al = __expf(mold - mnew);
        alpha_sh[row] = al;
        m_run[row] = mnew;
        l_run[row] = l_run[row] * al + sum;
      }
    }
    __syncthreads();
#pragma unroll
    for (int nti = 0; nti < 2; nti++) {
      const int nt = w * 2 + nti;
      floatx4_t& o = nti ? o1 : o0;
#pragma unroll
      for (int r = 0; r < 4; r++) o[r] *= alpha_sh[quad * 4 + r];
      const unsigned short* vp = vT + (size_t)(kvh * 128 + nt * 16 + l16) * SEQ + kb0 + quad * 8;
#pragma unroll
      for (int ks = 0; ks < 4; ks++) {
        bf16x8_t af = __builtin_bit_cast(bf16x8_t,
            *(const short8_t*)(&Ps[l16 * 136 + ks * 32 + quad * 8]));
        bf16x8_t bfv = __builtin_bit_cast(bf16x8_t, *(const short8_t*)(vp + ks * 32));
        o = __builtin_amdgcn_mfma_f32_16x16x32_bf16(af, bfv, o, 0, 0, 0);
      }
    }
    __syncthreads();
  }
#pragma unroll
  for (int nti = 0; nti < 2; nti++) {
    const int nt = w * 2 + nti;
    const floatx4_t& o = nti ? o1 : o0;
#pragma unroll
    for (int r = 0; r < 4; r++) {
      const int row = quad * 4 + r;
      float v = o[r] / l_run[row];
      attn_out[(size_t)(q0 + row) * 4096 + h * 128 + nt * 16 + l16] =
          (unsigned short)f2bf_bits(v);
    }
  }
}

extern "C" void kernel_launch(void* const* d_in, const int* in_sizes, int n_in,
                              void* d_out, int out_size, void* d_ws, size_t ws_size,
                              hipStream_t stream) {
  (void)in_sizes; (void)n_in; (void)out_size;
  const float* x    = (const float*)d_in[0];
  const float* wq   = (const float*)d_in[1];
  const float* wk   = (const float*)d_in[2];
  const float* wv   = (const float*)d_in[3];
  const float* wo   = (const float*)d_in[4];
  const float* cosp = (const float*)d_in[5];
  const float* sinp = (const float*)d_in[6];
  float* out = (float*)d_out;
  char* ws = (char*)d_ws;

  const size_t FULL_NEED = 92274688;  // 92.3 MB
  if (ws_size >= FULL_NEED) {
    // Region map (with reuse):
    //   R1 @0       (33.6MB): wqb           -> attnb @0 (16.8MB), vTb @16.8MB (4.2MB)
    //   R2 @33.6MB  (33.6MB): xb | wkvb     -> wob
    //   qb  @67.1MB (16.8MB)
    //   kvb @83.9MB (8.4MB)
    unsigned short* wqb   = (unsigned short*)(ws);
    unsigned short* attnb = (unsigned short*)(ws);
    unsigned short* vTb   = (unsigned short*)(ws + 16777216);
    unsigned short* xb    = (unsigned short*)(ws + 33554432);
    unsigned short* wkvb  = (unsigned short*)(ws + 33554432 + 16777216);
    unsigned short* wob   = (unsigned short*)(ws + 33554432);
    unsigned short* qb    = (unsigned short*)(ws + 67108864);
    unsigned short* kvb   = (unsigned short*)(ws + 83886080);

    cvt_kernel<<<4096, 256, 0, stream>>>(x, xb, SEQ * DIM / 8);
    cvt_kernel<<<8192, 256, 0, stream>>>(wq, wqb, NH * HD * DIM / 8);
    cvt_kernel<<<2048, 256, 0, stream>>>(wk, wkvb, NKV * HD * DIM / 8);
    cvt_kernel<<<2048, 256, 0, stream>>>(wv, wkvb + (size_t)NKV * HD * DIM, NKV * HD * DIM / 8);
    gemm_bf16<unsigned short><<<dim3(32, 16), 256, 0, stream>>>(xb, wqb, qb, SEQ, 4096, DIM);
    gemm_bf16<unsigned short><<<dim3(16, 16), 256, 0, stream>>>(xb, wkvb, kvb, SEQ, 2048, DIM);
    cvt_kernel<<<8192, 256, 0, stream>>>(wo, wob, DIM * NH * HD / 8);  // after xb/wkvb dead
    rope_kernel<<<SEQ * NH * 64 / 256, 256, 0, stream>>>(qb, cosp, sinp, NH, 4096);
    rope_kernel<<<SEQ * NKV * 64 / 256, 256, 0, stream>>>(kvb, cosp, sinp, NKV, 2048);
    vtrans_kernel<<<dim3(16, 32), 256, 0, stream>>>(kvb + 1024, vTb);
    attn_kernel<<<dim3(SEQ / 16, NH), 256, 0, stream>>>(qb, kvb, vTb, attnb);
    gemm_bf16<float><<<dim3(32, 16), 256, 0, stream>>>(attnb, wob, out, SEQ, 4096, DIM);
  } else {
    // Fallback (46.2 MB): round-0 structure, fp32-staging GEMMs.
    unsigned short* qb    = (unsigned short*)(ws);
    unsigned short* kvb   = (unsigned short*)(ws + 16777216);
    unsigned short* vTb   = (unsigned short*)(ws + 25165824);
    unsigned short* attnb = (unsigned short*)(ws + 29360128);

    gemm_bt<float, unsigned short><<<dim3(32, 16), 256, 0, stream>>>(x, wq, qb, SEQ, 4096, DIM, 4096, 0);
    gemm_bt<float, unsigned short><<<dim3(8, 16), 256, 0, stream>>>(x, wk, kvb, SEQ, 1024, DIM, 2048, 0);
    gemm_bt<float, unsigned short><<<dim3(8, 16), 256, 0, stream>>>(x, wv, kvb, SEQ, 1024, DIM, 2048, 1024);
    rope_kernel<<<SEQ * NH * 64 / 256, 256, 0, stream>>>(qb, cosp, sinp, NH, 4096);
    rope_kernel<<<SEQ * NKV * 64 / 256, 256, 0, stream>>>(kvb, cosp, sinp, NKV, 2048);
    vtrans_kernel<<<dim3(16, 32), 256, 0, stream>>>(kvb + 1024, vTb);
    attn_kernel<<<dim3(SEQ / 16, NH), 256, 0, stream>>>(qb, kvb, vTb, attnb);
    gemm_bt<unsigned short, float><<<dim3(32, 16), 256, 0, stream>>>(attnb, wo, out, SEQ, 4096, DIM, 4096, 0);
  }
}